// Round 8
// baseline (1622.309 us; speedup 1.0000x reference)
//
#include <hip/hip_runtime.h>
#include <hip/hip_bf16.h>
#include <cstdint>
#include <cstddef>

#define NN   100000
#define NE   1600000
#define HID  256
#define OUTC 40

typedef __attribute__((ext_vector_type(8))) short bf16x8;
typedef __attribute__((ext_vector_type(4))) float f32x4;

static __device__ __forceinline__ ushort f2bf(float f) {
    __hip_bfloat16 h = __float2bfloat16(f);
    return *reinterpret_cast<ushort*>(&h);
}
static __device__ __forceinline__ float bflo(unsigned u) { return __uint_as_float(u << 16); }
static __device__ __forceinline__ float bfhi(unsigned u) { return __uint_as_float(u & 0xffff0000u); }
static __device__ __forceinline__ float sb(unsigned w, int k) {
    return (float)((int)(w << (24 - 8 * k)) >> 24);
}

// ---------------- CSR build ----------------
__global__ void k_count(const int* __restrict__ dst, int* __restrict__ cnt) {
    int i = blockIdx.x * blockDim.x + threadIdx.x;
    if (i < NE) atomicAdd(&cnt[dst[i]], 1);
}

__global__ void k_blocksum(const int* __restrict__ cnt, int* __restrict__ bsum) {
    __shared__ int s[256];
    int t = threadIdx.x;
    int n = blockIdx.x * 256 + t;
    s[t] = (n < NN) ? cnt[n] : 0;
    __syncthreads();
    for (int off = 128; off; off >>= 1) {
        if (t < off) s[t] += s[t + off];
        __syncthreads();
    }
    if (t == 0) bsum[blockIdx.x] = s[0];
}

__global__ void k_scanblock(const int* __restrict__ bsum, int* __restrict__ boff, int nb) {
    __shared__ int s[512];
    int t = threadIdx.x;
    int v = (t < nb) ? bsum[t] : 0;
    s[t] = v;
    __syncthreads();
    for (int off = 1; off < 512; off <<= 1) {
        int u = (t >= off) ? s[t - off] : 0;
        __syncthreads();
        s[t] += u;
        __syncthreads();
    }
    if (t < nb) boff[t] = s[t] - v;
}

__global__ void k_rowptr(const int* __restrict__ cnt, const int* __restrict__ boff,
                         int* __restrict__ rowptr, int* __restrict__ fillp,
                         float* __restrict__ invd) {
    __shared__ int s[256];
    int t = threadIdx.x;
    int n = blockIdx.x * 256 + t;
    int c = (n < NN) ? cnt[n] : 0;
    s[t] = c;
    __syncthreads();
    for (int off = 1; off < 256; off <<= 1) {
        int u = (t >= off) ? s[t - off] : 0;
        __syncthreads();
        s[t] += u;
        __syncthreads();
    }
    if (n < NN) {
        int excl = boff[blockIdx.x] + s[t] - c;
        rowptr[n] = excl;
        fillp[n]  = excl;
        invd[n]   = 1.0f / (float)(c > 1 ? c : 1);
    }
    if (n == 0) rowptr[NN] = NE;
}

__global__ void k_fill(const int* __restrict__ src, const int* __restrict__ dst,
                       int* __restrict__ fillp, int* __restrict__ colidx) {
    int i = blockIdx.x * blockDim.x + threadIdx.x;
    if (i < NE) {
        int p = atomicAdd(&fillp[dst[i]], 1);
        colidx[p] = src[i];
    }
}

// ---------------- degree counting-sort -> perm ----------------
__global__ void k_dhist(const int* __restrict__ rowptr, int* __restrict__ dh) {
    int n = blockIdx.x * 256 + threadIdx.x;
    if (n < NN) {
        int d = rowptr[n + 1] - rowptr[n];
        atomicAdd(&dh[d < 127 ? d : 127], 1);
    }
}

__global__ void k_dscan(const int* __restrict__ dh, int* __restrict__ doff) {
    __shared__ int s[128];
    int t = threadIdx.x;
    int v = dh[t];
    s[t] = v;
    __syncthreads();
    for (int off = 1; off < 128; off <<= 1) {
        int u = (t >= off) ? s[t - off] : 0;
        __syncthreads();
        s[t] += u;
        __syncthreads();
    }
    doff[t] = s[t] - v;
}

__global__ void k_dperm(const int* __restrict__ rowptr, int* __restrict__ doff,
                        int* __restrict__ perm) {
    int n = blockIdx.x * 256 + threadIdx.x;
    if (n < NN) {
        int d = rowptr[n + 1] - rowptr[n];
        int pos = atomicAdd(&doff[d < 127 ? d : 127], 1);
        perm[pos] = n;
    }
}

// ---------------- fp32 -> bf16 conversion (weights) ----------------
__global__ void k_cvt4(const float* __restrict__ srcp, ushort* __restrict__ dstp, int n4) {
    int i = blockIdx.x * blockDim.x + threadIdx.x;
    if (i < n4) {
        float4 f = ((const float4*)srcp)[i];
        uint2 o;
        o.x = (unsigned)f2bf(f.x) | ((unsigned)f2bf(f.y) << 16);
        o.y = (unsigned)f2bf(f.z) | ((unsigned)f2bf(f.w) << 16);
        ((uint2*)dstp)[i] = o;
    }
}

// ---------------- global absmax of fp32 array ----------------
__global__ void k_gmaxf(const float* __restrict__ p, int n4, unsigned* __restrict__ gm) {
    int stride = gridDim.x * blockDim.x;
    float m = 0.f;
    for (int i = blockIdx.x * blockDim.x + threadIdx.x; i < n4; i += stride) {
        float4 v = ((const float4*)p)[i];
        m = fmaxf(m, fmaxf(fmaxf(fabsf(v.x), fabsf(v.y)), fmaxf(fabsf(v.z), fabsf(v.w))));
    }
    #pragma unroll
    for (int off = 32; off; off >>= 1) m = fmaxf(m, __shfl_xor(m, off));
    if ((threadIdx.x & 63) == 0) atomicMax(gm, __float_as_uint(m));
}

// ---------------- x fp32 [N,128] -> biased u8 with GLOBAL scale ----------------
__global__ __launch_bounds__(256) void k_quant_x8g(const float* __restrict__ x,
                                                   const unsigned* __restrict__ gm,
                                                   unsigned* __restrict__ xq) {
    int t = threadIdx.x;
    int qw = t >> 4, ql = t & 15;
    int row = blockIdx.x * 16 + qw;
    if (row >= NN) return;
    float g = __uint_as_float(gm[0]);
    float inv = (g > 0.f) ? 127.f / g : 0.f;
    const float4* p = (const float4*)(x + (size_t)row * 128 + ql * 8);
    float4 a = p[0], b = p[1];
    float v[8] = {a.x, a.y, a.z, a.w, b.x, b.y, b.z, b.w};
    unsigned w0 = 0, w1 = 0;
    #pragma unroll
    for (int k = 0; k < 4; ++k)
        w0 |= ((unsigned)((int)rintf(v[k] * inv) + 128) & 255u) << (8 * k);
    #pragma unroll
    for (int k = 0; k < 4; ++k)
        w1 |= ((unsigned)((int)rintf(v[4 + k] * inv) + 128) & 255u) << (8 * k);
    *(uint2*)(xq + (size_t)row * 32 + ql * 2) = make_uint2(w0, w1);
}

// ---------------- h0 row maxes (bf16, >=0) + global max ----------------
__global__ __launch_bounds__(256) void k_rowmax_h(const ushort* __restrict__ h,
                                                  float* __restrict__ rmax,
                                                  unsigned* __restrict__ gm) {
    int t = threadIdx.x;
    int qw = t >> 4, ql = t & 15;
    int row = blockIdx.x * 16 + qw;
    if (row >= NN) return;
    const uint4* p = (const uint4*)(h + (size_t)row * 256 + ql * 16);
    uint4 a = p[0], b = p[1];
    float m = 0.f;
    m = fmaxf(m, fmaxf(bflo(a.x), bfhi(a.x))); m = fmaxf(m, fmaxf(bflo(a.y), bfhi(a.y)));
    m = fmaxf(m, fmaxf(bflo(a.z), bfhi(a.z))); m = fmaxf(m, fmaxf(bflo(a.w), bfhi(a.w)));
    m = fmaxf(m, fmaxf(bflo(b.x), bfhi(b.x))); m = fmaxf(m, fmaxf(bflo(b.y), bfhi(b.y)));
    m = fmaxf(m, fmaxf(bflo(b.z), bfhi(b.z))); m = fmaxf(m, fmaxf(bflo(b.w), bfhi(b.w)));
    m = fmaxf(m, __shfl_xor(m, 1));
    m = fmaxf(m, __shfl_xor(m, 2));
    m = fmaxf(m, __shfl_xor(m, 4));
    m = fmaxf(m, __shfl_xor(m, 8));
    if (ql == 0) {
        rmax[row] = m;
        atomicMax(gm, __float_as_uint(m));
    }
}

// ---------------- h0 -> per-row int8 (self) + global-scale u4 (gather) ----------------
__global__ __launch_bounds__(256) void k_quant_h84g(const ushort* __restrict__ h,
                                                    const float* __restrict__ rmax,
                                                    const unsigned* __restrict__ gm,
                                                    char* __restrict__ hq8, float* __restrict__ s8,
                                                    unsigned* __restrict__ hq4) {
    int t = threadIdx.x;
    int qw = t >> 4, ql = t & 15;
    int row = blockIdx.x * 16 + qw;
    if (row >= NN) return;
    const uint4* p = (const uint4*)(h + (size_t)row * 256 + ql * 16);
    uint4 a = p[0], b = p[1];
    float v[16];
    v[0]  = bflo(a.x); v[1]  = bfhi(a.x); v[2]  = bflo(a.y); v[3]  = bfhi(a.y);
    v[4]  = bflo(a.z); v[5]  = bfhi(a.z); v[6]  = bflo(a.w); v[7]  = bfhi(a.w);
    v[8]  = bflo(b.x); v[9]  = bfhi(b.x); v[10] = bflo(b.y); v[11] = bfhi(b.y);
    v[12] = bflo(b.z); v[13] = bfhi(b.z); v[14] = bflo(b.w); v[15] = bfhi(b.w);
    float rm = rmax[row];
    float g  = __uint_as_float(gm[0]);
    float inv8 = (rm > 0.f) ? 127.f / rm : 0.f;
    float inv4 = (g > 0.f) ? 15.f / g : 0.f;
    unsigned wo[4];
    #pragma unroll
    for (int wi = 0; wi < 4; ++wi) {
        unsigned w = 0;
        #pragma unroll
        for (int k = 0; k < 4; ++k)
            w |= ((unsigned)(unsigned char)(char)(int)rintf(v[wi * 4 + k] * inv8)) << (8 * k);
        wo[wi] = w;
    }
    *(uint4*)(hq8 + (size_t)row * 256 + ql * 16) = make_uint4(wo[0], wo[1], wo[2], wo[3]);
    unsigned lo = 0, hi = 0;
    #pragma unroll
    for (int k = 0; k < 8; ++k)
        lo |= ((unsigned)(int)rintf(v[k] * inv4) & 15u) << (4 * k);
    #pragma unroll
    for (int k = 0; k < 8; ++k)
        hi |= ((unsigned)(int)rintf(v[8 + k] * inv4) & 15u) << (4 * k);
    *(uint2*)(hq4 + (size_t)row * 32 + ql * 2) = make_uint2(lo, hi);
    if (ql == 0) s8[row] = (rm > 0.f) ? rm / 127.f : 0.f;
}

// ---------------- fused layer: global-scale packed gather (u16 int accum) + dual bf16 MFMA ----------------
// PBITS=8: payload uint4/lane (16 u8 feats). PBITS=4: payload uint2/lane (16 nibble feats).
// Each lane owns 16 features; LPR = D/16 lanes per row. colidx loaded lane-parallel per
// LPR-edge window and broadcast via __shfl. BIAS subtracted as BIAS*deg at dequant.
template<int D, int PBITS, bool SELF_F32, int BIAS>
__global__ __launch_bounds__(256, 4) void k_layerg(
    const unsigned* __restrict__ qpk, const unsigned* __restrict__ gm,
    const void* __restrict__ selfp, const float* __restrict__ selfs,
    const ushort* __restrict__ Wl, const ushort* __restrict__ Wr,
    const float* __restrict__ bias, const float* __restrict__ invd,
    const int* __restrict__ rowptr, const int* __restrict__ colidx,
    const int* __restrict__ perm,
    ushort* __restrict__ hout)
{
    __shared__ ushort aggS[64 * D];
    char* aggSb = (char*)aggS;
    const int t  = threadIdx.x;
    const int r0 = blockIdx.x * 64;
    constexpr int LPR = D / 16;
    constexpr int GPB = 256 / LPR;
    constexpr int RWW = (PBITS == 8) ? D / 4 : D / 8;   // words per row
    const int gid = t / LPR, li = t % LPR;
    const int l = t & 63;
    const int base = l & ~(LPR - 1);

    const float gmax = __uint_as_float(gm[0]);
    const float gscale = (gmax > 0.f) ? gmax / ((PBITS == 8) ? 127.f : 15.f) : 0.f;

    // ---- phase 1: integer mean-aggregate into LDS bf16 ----
    for (int rr = gid; rr < 64; rr += GPB) {
        const int rg0 = r0 + rr;
        const int r = (rg0 < NN) ? perm[rg0] : -1;
        unsigned acc[8] = {0, 0, 0, 0, 0, 0, 0, 0};
        int deg = 0; float iv = 0.f;
        if (r >= 0) {
            const int beg = rowptr[r], end = rowptr[r + 1];
            deg = end - beg;
            iv = invd[r];
            for (int e0 = beg; e0 < end; e0 += LPR) {
                const int cnt = end - e0;
                const int myc = (li < cnt) ? colidx[e0 + li] : 0;
                #pragma unroll
                for (int b = 0; b < LPR; b += 8) {
                    if (b < cnt) {
                        if (PBITS == 4) {
                            uint2 u[8];
                            #pragma unroll
                            for (int j = 0; j < 8; ++j) {
                                int sj = __shfl(myc, base + b + j);
                                u[j] = (b + j < cnt)
                                    ? *(const uint2*)(qpk + (size_t)sj * RWW + li * 2)
                                    : make_uint2(0u, 0u);
                            }
                            #pragma unroll
                            for (int j = 0; j < 8; ++j) {
                                #pragma unroll
                                for (int s = 0; s < 4; ++s) {
                                    acc[s]     += (u[j].x >> (4 * s)) & 0x000F000Fu;
                                    acc[4 + s] += (u[j].y >> (4 * s)) & 0x000F000Fu;
                                }
                            }
                        } else {
                            uint4 u[8];
                            #pragma unroll
                            for (int j = 0; j < 8; ++j) {
                                int sj = __shfl(myc, base + b + j);
                                u[j] = (b + j < cnt)
                                    ? *(const uint4*)(qpk + (size_t)sj * RWW + li * 4)
                                    : make_uint4(0u, 0u, 0u, 0u);
                            }
                            #pragma unroll
                            for (int j = 0; j < 8; ++j) {
                                #pragma unroll
                                for (int wi = 0; wi < 4; ++wi) {
                                    unsigned w = (&u[j].x)[wi];
                                    acc[2 * wi]     += w & 0x00FF00FFu;
                                    acc[2 * wi + 1] += (w >> 8) & 0x00FF00FFu;
                                }
                            }
                        }
                    }
                }
            }
        }
        const float K1 = gscale * iv;
        const float K2 = (float)(BIAS * deg) * K1;
        float v16[16];
        if (PBITS == 4) {
            #pragma unroll
            for (int s = 0; s < 4; ++s) {
                v16[s]      = (float)(acc[s] & 0xFFFFu) * K1 - K2;
                v16[s + 4]  = (float)(acc[s] >> 16)     * K1 - K2;
                v16[8 + s]  = (float)(acc[4 + s] & 0xFFFFu) * K1 - K2;
                v16[12 + s] = (float)(acc[4 + s] >> 16)     * K1 - K2;
            }
        } else {
            #pragma unroll
            for (int wi = 0; wi < 4; ++wi) {
                v16[4 * wi + 0] = (float)(acc[2 * wi] & 0xFFFFu)     * K1 - K2;
                v16[4 * wi + 2] = (float)(acc[2 * wi] >> 16)         * K1 - K2;
                v16[4 * wi + 1] = (float)(acc[2 * wi + 1] & 0xFFFFu) * K1 - K2;
                v16[4 * wi + 3] = (float)(acc[2 * wi + 1] >> 16)     * K1 - K2;
            }
        }
        #pragma unroll
        for (int gg = 0; gg < 2; ++gg) {
            unsigned q0 = (unsigned)f2bf(v16[gg*8+0]) | ((unsigned)f2bf(v16[gg*8+1]) << 16);
            unsigned q1 = (unsigned)f2bf(v16[gg*8+2]) | ((unsigned)f2bf(v16[gg*8+3]) << 16);
            unsigned q2 = (unsigned)f2bf(v16[gg*8+4]) | ((unsigned)f2bf(v16[gg*8+5]) << 16);
            unsigned q3 = (unsigned)f2bf(v16[gg*8+6]) | ((unsigned)f2bf(v16[gg*8+7]) << 16);
            int g  = li * 2 + gg;
            int gs = g ^ (rr & 7);
            *(uint4*)(aggSb + (size_t)rr * (D * 2) + (gs << 4)) = make_uint4(q0, q1, q2, q3);
        }
    }
    __syncthreads();

    // ---- phase 2: per-wave 16-row MFMA GEMM over HID in 16-col chunks ----
    const int w = t >> 6, lm = l & 15, lk = l >> 4;
    const int rr = w * 16 + lm;
    const int rgl = r0 + rr;
    const int ar = (rgl < NN) ? perm[rgl] : -1;

    int arow[4];
    #pragma unroll
    for (int i = 0; i < 4; ++i) {
        int og = r0 + w * 16 + lk * 4 + i;
        arow[i] = (og < NN) ? perm[og] : -1;
    }

    bf16x8 ax[D / 32];
    if (SELF_F32) {
        const float* xf = (const float*)selfp;
        #pragma unroll
        for (int kk = 0; kk < D / 32; ++kk) {
            bf16x8 v;
            if (ar >= 0) {
                const float4* p = (const float4*)(xf + (size_t)ar * D + kk * 32 + lk * 8);
                float4 f0 = p[0], f1 = p[1];
                v[0] = (short)f2bf(f0.x); v[1] = (short)f2bf(f0.y);
                v[2] = (short)f2bf(f0.z); v[3] = (short)f2bf(f0.w);
                v[4] = (short)f2bf(f1.x); v[5] = (short)f2bf(f1.y);
                v[6] = (short)f2bf(f1.z); v[7] = (short)f2bf(f1.w);
            } else v = (bf16x8)(short)0;
            ax[kk] = v;
        }
    } else {
        const char* hq = (const char*)selfp;
        const float sr = (ar >= 0) ? selfs[ar] : 0.f;
        #pragma unroll
        for (int kk = 0; kk < D / 32; ++kk) {
            uint2 uq = (ar >= 0)
                ? *(const uint2*)(hq + (size_t)ar * D + kk * 32 + lk * 8)
                : make_uint2(0u, 0u);
            bf16x8 v;
            v[0] = (short)f2bf(sr * sb(uq.x, 0));
            v[1] = (short)f2bf(sr * sb(uq.x, 1));
            v[2] = (short)f2bf(sr * sb(uq.x, 2));
            v[3] = (short)f2bf(sr * sb(uq.x, 3));
            v[4] = (short)f2bf(sr * sb(uq.y, 0));
            v[5] = (short)f2bf(sr * sb(uq.y, 1));
            v[6] = (short)f2bf(sr * sb(uq.y, 2));
            v[7] = (short)f2bf(sr * sb(uq.y, 3));
            ax[kk] = v;
        }
    }

    for (int cc = 0; cc < HID / 16; ++cc) {
        const int c = cc * 16 + lm;
        f32x4 acc = {0.f, 0.f, 0.f, 0.f};
        #pragma unroll
        for (int kk = 0; kk < D / 32; ++kk) {
            int g  = kk * 4 + lk;
            int gs = g ^ (rr & 7);
            bf16x8 a_agg = *(const bf16x8*)(aggSb + (size_t)rr * (D * 2) + (gs << 4));
            bf16x8 bl = *(const bf16x8*)(Wl + (size_t)c * D + kk * 32 + lk * 8);
            bf16x8 br = *(const bf16x8*)(Wr + (size_t)c * D + kk * 32 + lk * 8);
            acc = __builtin_amdgcn_mfma_f32_16x16x32_bf16(a_agg, bl, acc, 0, 0, 0);
            acc = __builtin_amdgcn_mfma_f32_16x16x32_bf16(ax[kk], br, acc, 0, 0, 0);
        }
        const float bv = bias[c];
        #pragma unroll
        for (int i = 0; i < 4; ++i) {
            if (arow[i] >= 0) {
                float v = fmaxf(acc[i] + bv, 0.f);
                hout[(size_t)arow[i] * HID + c] = f2bf(v);
            }
        }
    }
}

// ---------------- premul: q = int8(h1@Wlo^T)+sq, r = h1@Wro^T+bo ----------------
__global__ __launch_bounds__(256, 4) void k_premul(
    const ushort* __restrict__ h1, const ushort* __restrict__ wlo,
    const ushort* __restrict__ wro, const float* __restrict__ bo,
    char* __restrict__ qq, float* __restrict__ sq, float* __restrict__ rbuf)
{
    const int t = threadIdx.x;
    const int r0 = blockIdx.x * 64;
    const int w = t >> 6, l = t & 63, lm = l & 15, lk = l >> 4;
    const int rr = w * 16 + lm;
    const int rg = r0 + rr;

    f32x4 aq[3], ar[3];
    #pragma unroll
    for (int cc = 0; cc < 3; ++cc) { aq[cc] = {0.f,0.f,0.f,0.f}; ar[cc] = {0.f,0.f,0.f,0.f}; }

    #pragma unroll
    for (int kk = 0; kk < 8; ++kk) {
        bf16x8 a = (rg < NN)
            ? *(const bf16x8*)(h1 + (size_t)rg * 256 + kk * 32 + lk * 8)
            : (bf16x8)(short)0;
        #pragma unroll
        for (int cc = 0; cc < 3; ++cc) {
            const int c = cc * 16 + lm;
            bf16x8 bl = (c < OUTC) ? *(const bf16x8*)(wlo + (size_t)c * 256 + kk * 32 + lk * 8)
                                   : (bf16x8)(short)0;
            bf16x8 br = (c < OUTC) ? *(const bf16x8*)(wro + (size_t)c * 256 + kk * 32 + lk * 8)
                                   : (bf16x8)(short)0;
            aq[cc] = __builtin_amdgcn_mfma_f32_16x16x32_bf16(a, bl, aq[cc], 0, 0, 0);
            ar[cc] = __builtin_amdgcn_mfma_f32_16x16x32_bf16(a, br, ar[cc], 0, 0, 0);
        }
    }

    #pragma unroll
    for (int i = 0; i < 4; ++i) {
        const int orow = r0 + w * 16 + lk * 4 + i;
        if (orow >= NN) continue;
        float m = 0.f;
        #pragma unroll
        for (int cc = 0; cc < 3; ++cc) {
            const int c = cc * 16 + lm;
            if (c < OUTC) m = fmaxf(m, fabsf(aq[cc][i]));
        }
        m = fmaxf(m, __shfl_xor(m, 1));
        m = fmaxf(m, __shfl_xor(m, 2));
        m = fmaxf(m, __shfl_xor(m, 4));
        m = fmaxf(m, __shfl_xor(m, 8));
        const float inv = (m > 0.f) ? 127.f / m : 0.f;
        #pragma unroll
        for (int cc = 0; cc < 3; ++cc) {
            const int c = cc * 16 + lm;
            char qv = (c < OUTC) ? (char)(int)rintf(aq[cc][i] * inv) : (char)0;
            qq[(size_t)orow * 64 + c] = qv;
            rbuf[(size_t)orow * 64 + c] = (c < OUTC) ? (ar[cc][i] + bo[c]) : 0.f;
        }
        qq[(size_t)orow * 64 + 48 + lm] = (char)0;
        rbuf[(size_t)orow * 64 + 48 + lm] = 0.f;
        if (lm == 0) sq[orow] = m / 127.f;
    }
}

// ---------------- final: out = log_softmax(mean_agg(q) + r) ----------------
__global__ __launch_bounds__(256) void k_final(
    const char* __restrict__ qq, const float* __restrict__ sq,
    const float* __restrict__ rbuf, const float* __restrict__ invd,
    const int* __restrict__ rowptr, const int* __restrict__ colidx,
    float* __restrict__ out)
{
    const int t = threadIdx.x;
    const int g = t >> 2, li = t & 3;
    const int row = blockIdx.x * 64 + g;
    if (row >= NN) return;

    float acc[16];
    #pragma unroll
    for (int k = 0; k < 16; ++k) acc[k] = 0.f;

    const int beg = rowptr[row], end = rowptr[row + 1];
    for (int e = beg; e < end; e += 8) {
        int sidx[8];
        #pragma unroll
        for (int j = 0; j < 8; ++j) sidx[j] = (e + j < end) ? colidx[e + j] : -1;
        uint4 u[8]; float sc[8];
        #pragma unroll
        for (int j = 0; j < 8; ++j) {
            if (sidx[j] >= 0) {
                u[j]  = *(const uint4*)(qq + (size_t)sidx[j] * 64 + li * 16);
                sc[j] = sq[sidx[j]];
            } else { u[j] = make_uint4(0u, 0u, 0u, 0u); sc[j] = 0.f; }
        }
        #pragma unroll
        for (int j = 0; j < 8; ++j) {
            #pragma unroll
            for (int wi = 0; wi < 4; ++wi) {
                unsigned w = (&u[j].x)[wi];
                acc[wi*4+0] = fmaf(sc[j], sb(w, 0), acc[wi*4+0]);
                acc[wi*4+1] = fmaf(sc[j], sb(w, 1), acc[wi*4+1]);
                acc[wi*4+2] = fmaf(sc[j], sb(w, 2), acc[wi*4+2]);
                acc[wi*4+3] = fmaf(sc[j], sb(w, 3), acc[wi*4+3]);
            }
        }
    }

    const float iv = invd[row];
    const float4* rp = (const float4*)(rbuf + (size_t)row * 64 + li * 16);
    float v[16];
    #pragma unroll
    for (int ch = 0; ch < 4; ++ch) {
        float4 rv = rp[ch];
        v[ch*4+0] = acc[ch*4+0] * iv + rv.x;
        v[ch*4+1] = acc[ch*4+1] * iv + rv.y;
        v[ch*4+2] = acc[ch*4+2] * iv + rv.z;
        v[ch*4+3] = acc[ch*4+3] * iv + rv.w;
    }
    #pragma unroll
    for (int k = 0; k < 16; ++k)
        if (li * 16 + k >= OUTC) v[k] = -INFINITY;

    float m = v[0];
    #pragma unroll
    for (int k = 1; k < 16; ++k) m = fmaxf(m, v[k]);
    m = fmaxf(m, __shfl_xor(m, 1));
    m = fmaxf(m, __shfl_xor(m, 2));

    float s = 0.f;
    #pragma unroll
    for (int k = 0; k < 16; ++k)
        if (li * 16 + k < OUTC) s += __expf(v[k] - m);
    s += __shfl_xor(s, 1);
    s += __shfl_xor(s, 2);
    const float ls = __logf(s);

    #pragma unroll
    for (int ch = 0; ch < 4; ++ch) {
        const int c = li * 16 + ch * 4;
        if (c < OUTC) {
            float4 o;
            o.x = v[ch*4+0] - m - ls;
            o.y = v[ch*4+1] - m - ls;
            o.z = v[ch*4+2] - m - ls;
            o.w = v[ch*4+3] - m - ls;
            *(float4*)(out + (size_t)row * OUTC + c) = o;
        }
    }
}

extern "C" void kernel_launch(void* const* d_in, const int* in_sizes, int n_in,
                              void* d_out, int out_size, void* d_ws, size_t ws_size,
                              hipStream_t stream) {
    const float* x   = (const float*)d_in[0];
    const int*   ei  = (const int*)d_in[1];
    const int*   src = ei;
    const int*   dst = ei + NE;
    const float* Wl0 = (const float*)d_in[2];
    const float* Wr0 = (const float*)d_in[3];
    const float* b0  = (const float*)d_in[4];
    const float* Wl1 = (const float*)d_in[5];
    const float* Wr1 = (const float*)d_in[6];
    const float* b1  = (const float*)d_in[7];
    const float* Wlo = (const float*)d_in[8];
    const float* Wro = (const float*)d_in[9];
    const float* bo  = (const float*)d_in[10];
    float* out = (float*)d_out;

    char* ws = (char*)d_ws;
    const size_t MB = 1 << 20;
    float*    invd   = (float*)(ws + 0);
    int*      rowptr = (int*)(ws + MB / 2);
    int*      cnt    = (int*)(ws + MB);
    int*      fillp  = (int*)(ws + MB + MB / 2);
    int*      bsum   = (int*)(ws + 2 * MB);
    int*      boff   = (int*)(ws + 2 * MB + MB / 8);
    int*      dh     = (int*)(ws + 2 * MB + MB / 4);
    int*      doff   = (int*)(ws + 2 * MB + MB / 4 + 1024);
    unsigned* gmx    = (unsigned*)(ws + 2 * MB + MB / 2);
    unsigned* gmh    = (unsigned*)(ws + 2 * MB + MB / 2 + 64);
    float*    rmax   = (float*)(ws + 2 * MB + 3 * MB / 4);
    float*    s8     = (float*)(ws + 3 * MB + MB / 4);
    float*    sq     = (float*)(ws + 3 * MB + 3 * MB / 4);
    ushort*   Wb     = (ushort*)(ws + 4 * MB + MB / 4);
    int*      perm   = (int*)(ws + 5 * MB);
    int*      colidx = (int*)(ws + 6 * MB);              // 6.4MB -> ends 12.4
    unsigned* xq8    = (unsigned*)(ws + 13 * MB);        // [N,128B] = 12.8MB (13..25.8)
    unsigned* h0q4   = (unsigned*)(ws + 13 * MB);        // aliases xq8 (dead after layer0)
    char*     qq     = (char*)(ws + 13 * MB);            // aliases h0q4 (dead after layer1)
    ushort*   h0     = (ushort*)(ws + 26 * MB);          // [N,256] bf16 = 51.2MB (26..77.2)
    ushort*   h1     = (ushort*)(ws + 26 * MB);          // aliases h0 (self uses h0q8)
    char*     h0q8   = (char*)(ws + 78 * MB);            // [N,256] int8 = 25.6MB (78..103.6)
    float*    rbuf   = (float*)(ws + 78 * MB);           // aliases h0q8 (dead after layer1)

    ushort* wl0 = Wb;
    ushort* wr0 = Wb + 32768;
    ushort* wl1 = Wb + 65536;
    ushort* wr1 = Wb + 131072;
    ushort* wlo = Wb + 196608;
    ushort* wro = Wb + 206848;

    // resets
    hipMemsetAsync(cnt, 0, NN * sizeof(int), stream);
    hipMemsetAsync(dh, 0, 128 * sizeof(int), stream);
    hipMemsetAsync(gmx, 0, 128, stream);   // covers gmx+gmh

    // CSR build
    k_count<<<(NE + 255) / 256, 256, 0, stream>>>(dst, cnt);
    const int NB = (NN + 255) / 256;  // 391
    k_blocksum<<<NB, 256, 0, stream>>>(cnt, bsum);
    k_scanblock<<<1, 512, 0, stream>>>(bsum, boff, NB);
    k_rowptr<<<NB, 256, 0, stream>>>(cnt, boff, rowptr, fillp, invd);
    k_fill<<<(NE + 255) / 256, 256, 0, stream>>>(src, dst, fillp, colidx);

    // degree-sorted permutation
    k_dhist<<<NB, 256, 0, stream>>>(rowptr, dh);
    k_dscan<<<1, 128, 0, stream>>>(dh, doff);
    k_dperm<<<NB, 256, 0, stream>>>(rowptr, doff, perm);

    // weights -> bf16; x -> global-scale biased u8
    k_cvt4<<<(32768/4 + 255) / 256, 256, 0, stream>>>(Wl0, wl0, 32768/4);
    k_cvt4<<<(32768/4 + 255) / 256, 256, 0, stream>>>(Wr0, wr0, 32768/4);
    k_cvt4<<<(65536/4 + 255) / 256, 256, 0, stream>>>(Wl1, wl1, 65536/4);
    k_cvt4<<<(65536/4 + 255) / 256, 256, 0, stream>>>(Wr1, wr1, 65536/4);
    k_cvt4<<<(10240/4 + 255) / 256, 256, 0, stream>>>(Wlo, wlo, 10240/4);
    k_cvt4<<<(10240/4 + 255) / 256, 256, 0, stream>>>(Wro, wro, 10240/4);
    k_gmaxf<<<2048, 256, 0, stream>>>(x, NN * 32, gmx);
    k_quant_x8g<<<(NN + 15) / 16, 256, 0, stream>>>(x, gmx, xq8);

    const int GB = (NN + 63) / 64;  // 1563
    // layer 0: gather biased-u8 x (global scale), self fp32 x -> h0 bf16
    k_layerg<128, 8, true, 128><<<GB, 256, 0, stream>>>(
        xq8, gmx, x, nullptr, wl0, wr0, b0, invd, rowptr, colidx, perm, h0);
    // h0 row maxes + global max, then quantize (int8 self per-row + u4 global gather)
    k_rowmax_h<<<(NN + 15) / 16, 256, 0, stream>>>(h0, rmax, gmh);
    k_quant_h84g<<<(NN + 15) / 16, 256, 0, stream>>>(h0, rmax, gmh, h0q8, s8, h0q4);
    // layer 1: gather u4 h0 (global scale), self int8 per-row -> h1 bf16
    k_layerg<256, 4, false, 0><<<GB, 256, 0, stream>>>(
        h0q4, gmh, h0q8, s8, wl1, wr1, b1, invd, rowptr, colidx, perm, h1);
    // layer 2 restructured: premul then 1-line-per-edge gather + softmax
    k_premul<<<GB, 256, 0, stream>>>(h1, wlo, wro, bo, qq, sq, rbuf);
    k_final<<<(NN + 63) / 64, 256, 0, stream>>>(qq, sq, rbuf, invd, rowptr, colidx, out);
}

// Round 9
// 522.815 us; speedup vs baseline: 3.1030x; 3.1030x over previous
//
#include <hip/hip_runtime.h>
#include <hip/hip_bf16.h>
#include <cstdint>
#include <cstddef>

#define NN   100000
#define NE   1600000
#define HID  256
#define OUTC 40

typedef __attribute__((ext_vector_type(8))) short bf16x8;
typedef __attribute__((ext_vector_type(4))) float f32x4;

static __device__ __forceinline__ ushort f2bf(float f) {
    __hip_bfloat16 h = __float2bfloat16(f);
    return *reinterpret_cast<ushort*>(&h);
}
static __device__ __forceinline__ float bflo(unsigned u) { return __uint_as_float(u << 16); }
static __device__ __forceinline__ float bfhi(unsigned u) { return __uint_as_float(u & 0xffff0000u); }
static __device__ __forceinline__ float sb(unsigned w, int k) {
    return (float)((int)(w << (24 - 8 * k)) >> 24);
}

// ---------------- CSR build ----------------
__global__ void k_count(const int* __restrict__ dst, int* __restrict__ cnt) {
    int i = blockIdx.x * blockDim.x + threadIdx.x;
    if (i < NE) atomicAdd(&cnt[dst[i]], 1);
}

__global__ void k_blocksum(const int* __restrict__ cnt, int* __restrict__ bsum) {
    __shared__ int s[256];
    int t = threadIdx.x;
    int n = blockIdx.x * 256 + t;
    s[t] = (n < NN) ? cnt[n] : 0;
    __syncthreads();
    for (int off = 128; off; off >>= 1) {
        if (t < off) s[t] += s[t + off];
        __syncthreads();
    }
    if (t == 0) bsum[blockIdx.x] = s[0];
}

__global__ void k_scanblock(const int* __restrict__ bsum, int* __restrict__ boff, int nb) {
    __shared__ int s[512];
    int t = threadIdx.x;
    int v = (t < nb) ? bsum[t] : 0;
    s[t] = v;
    __syncthreads();
    for (int off = 1; off < 512; off <<= 1) {
        int u = (t >= off) ? s[t - off] : 0;
        __syncthreads();
        s[t] += u;
        __syncthreads();
    }
    if (t < nb) boff[t] = s[t] - v;
}

__global__ void k_rowptr(const int* __restrict__ cnt, const int* __restrict__ boff,
                         int* __restrict__ rowptr, int* __restrict__ fillp,
                         float* __restrict__ invd) {
    __shared__ int s[256];
    int t = threadIdx.x;
    int n = blockIdx.x * 256 + t;
    int c = (n < NN) ? cnt[n] : 0;
    s[t] = c;
    __syncthreads();
    for (int off = 1; off < 256; off <<= 1) {
        int u = (t >= off) ? s[t - off] : 0;
        __syncthreads();
        s[t] += u;
        __syncthreads();
    }
    if (n < NN) {
        int excl = boff[blockIdx.x] + s[t] - c;
        rowptr[n] = excl;
        fillp[n]  = excl;
        invd[n]   = 1.0f / (float)(c > 1 ? c : 1);
    }
    if (n == 0) rowptr[NN] = NE;
}

__global__ void k_fill(const int* __restrict__ src, const int* __restrict__ dst,
                       int* __restrict__ fillp, int* __restrict__ colidx) {
    int i = blockIdx.x * blockDim.x + threadIdx.x;
    if (i < NE) {
        int p = atomicAdd(&fillp[dst[i]], 1);
        colidx[p] = src[i];
    }
}

// ---------------- weights fp32 [OC][D] -> fragment-major bf16 ----------------
// frag f = (cc*(D/32)+kk)*64 + lk*16 + lm holds W[cc*16+lm][kk*32+lk*8 .. +8].
// Phase-2 lane l then reads packed[((cc*(D/32)+kk)*64 + l)*8] -> fully coalesced.
__global__ void k_cvtfrag(const float* __restrict__ W, ushort* __restrict__ dst,
                          int ocreal, int d, int nf) {
    int f = blockIdx.x * 256 + threadIdx.x;
    if (f >= nf) return;
    int lm = f & 15, lk = (f >> 4) & 3;
    int rest = f >> 6;
    int dk = d / 32;
    int kk = rest % dk, cc = rest / dk;
    int row = cc * 16 + lm, col = kk * 32 + lk * 8;
    unsigned q0 = 0, q1 = 0, q2 = 0, q3 = 0;
    if (row < ocreal) {
        const float4* p = (const float4*)(W + (size_t)row * d + col);
        float4 a = p[0], b = p[1];
        q0 = (unsigned)f2bf(a.x) | ((unsigned)f2bf(a.y) << 16);
        q1 = (unsigned)f2bf(a.z) | ((unsigned)f2bf(a.w) << 16);
        q2 = (unsigned)f2bf(b.x) | ((unsigned)f2bf(b.y) << 16);
        q3 = (unsigned)f2bf(b.z) | ((unsigned)f2bf(b.w) << 16);
    }
    *(uint4*)(dst + (size_t)f * 8) = make_uint4(q0, q1, q2, q3);
}

// ---------------- x fp32 [N,128] -> signed int4 (scale=rowmax/7) ----------------
__global__ __launch_bounds__(256) void k_quant_x4(const float* __restrict__ x,
                                                  unsigned* __restrict__ xq4,
                                                  float* __restrict__ sx4) {
    int t = threadIdx.x;
    int qw = t >> 4, ql = t & 15;
    int row = blockIdx.x * 16 + qw;
    if (row >= NN) return;
    const float4* p = (const float4*)(x + (size_t)row * 128 + ql * 8);
    float4 a = p[0], b = p[1];
    float v[8] = {a.x, a.y, a.z, a.w, b.x, b.y, b.z, b.w};
    float m = 0.f;
    #pragma unroll
    for (int k = 0; k < 8; ++k) m = fmaxf(m, fabsf(v[k]));
    m = fmaxf(m, __shfl_xor(m, 1));
    m = fmaxf(m, __shfl_xor(m, 2));
    m = fmaxf(m, __shfl_xor(m, 4));
    m = fmaxf(m, __shfl_xor(m, 8));
    float inv = (m > 0.f) ? 7.f / m : 0.f;
    unsigned w = 0;
    #pragma unroll
    for (int k = 0; k < 8; ++k)
        w |= ((unsigned)(int)rintf(v[k] * inv) & 15u) << (4 * k);
    xq4[(size_t)row * 16 + ql] = w;
    if (ql == 0) sx4[row] = (m > 0.f) ? m / 7.f : 0.f;
}

// ---------------- h0 bf16 [N,256] (>=0) -> int8 (self) + unsigned int4 (gather) ----------------
__global__ __launch_bounds__(256) void k_quant_h84(const ushort* __restrict__ h,
                                                   char* __restrict__ hq8, float* __restrict__ s8,
                                                   unsigned* __restrict__ hq4, float* __restrict__ s4) {
    int t = threadIdx.x;
    int qw = t >> 4, ql = t & 15;
    int row = blockIdx.x * 16 + qw;
    if (row >= NN) return;
    const uint4* p = (const uint4*)(h + (size_t)row * 256 + ql * 16);
    uint4 a = p[0], b = p[1];
    float v[16];
    v[0]  = bflo(a.x); v[1]  = bfhi(a.x); v[2]  = bflo(a.y); v[3]  = bfhi(a.y);
    v[4]  = bflo(a.z); v[5]  = bfhi(a.z); v[6]  = bflo(a.w); v[7]  = bfhi(a.w);
    v[8]  = bflo(b.x); v[9]  = bfhi(b.x); v[10] = bflo(b.y); v[11] = bfhi(b.y);
    v[12] = bflo(b.z); v[13] = bfhi(b.z); v[14] = bflo(b.w); v[15] = bfhi(b.w);
    float m = 0.f;
    #pragma unroll
    for (int k = 0; k < 16; ++k) m = fmaxf(m, v[k]);   // h >= 0
    m = fmaxf(m, __shfl_xor(m, 1));
    m = fmaxf(m, __shfl_xor(m, 2));
    m = fmaxf(m, __shfl_xor(m, 4));
    m = fmaxf(m, __shfl_xor(m, 8));
    float inv8 = (m > 0.f) ? 127.f / m : 0.f;
    float inv4 = (m > 0.f) ? 15.f / m : 0.f;
    unsigned wo[4];
    #pragma unroll
    for (int wi = 0; wi < 4; ++wi) {
        unsigned w = 0;
        #pragma unroll
        for (int k = 0; k < 4; ++k)
            w |= ((unsigned)(unsigned char)(char)(int)rintf(v[wi * 4 + k] * inv8)) << (8 * k);
        wo[wi] = w;
    }
    *(uint4*)(hq8 + (size_t)row * 256 + ql * 16) = make_uint4(wo[0], wo[1], wo[2], wo[3]);
    unsigned lo = 0, hi = 0;
    #pragma unroll
    for (int k = 0; k < 8; ++k)
        lo |= ((unsigned)(int)rintf(v[k] * inv4) & 15u) << (4 * k);
    #pragma unroll
    for (int k = 0; k < 8; ++k)
        hi |= ((unsigned)(int)rintf(v[8 + k] * inv4) & 15u) << (4 * k);
    *(uint2*)(hq4 + (size_t)row * 32 + ql * 2) = make_uint2(lo, hi);
    if (ql == 0) {
        s8[row] = (m > 0.f) ? m / 127.f : 0.f;
        s4[row] = (m > 0.f) ? m / 15.f  : 0.f;
    }
}

// ---------------- fused layer: int4 CSR mean-aggregate (LDS) + dual bf16 MFMA GEMM ----------------
// Phase 1 (R7-proven): D/16 lanes per row, 8-edge predicated batches, colidx staged in LDS.
// Phase 2: frag-major weights (coalesced), self from fp32 x (layer0) or int8 (layer1).
template<int D, bool SELF_F32, bool SIGNED>
__global__ __launch_bounds__(256, 4) void k_layer4(
    const unsigned* __restrict__ qin4, const float* __restrict__ qs4,
    const void* __restrict__ selfp, const float* __restrict__ selfs,
    const ushort* __restrict__ Wl, const ushort* __restrict__ Wr,   // frag-major
    const float* __restrict__ bias, const float* __restrict__ invd,
    const int* __restrict__ rowptr, const int* __restrict__ colidx,
    ushort* __restrict__ hout)        // [NN][HID] bf16, relu'd
{
    __shared__ ushort aggS[64 * D];
    __shared__ int cidxS[2048];
    char* aggSb = (char*)aggS;
    const int t  = threadIdx.x;
    const int r0 = blockIdx.x * 64;
    constexpr int LPR = D / 16;        // lanes per row (8 or 16)
    constexpr int GPB = 256 / LPR;     // row-groups per block (32 or 16)
    constexpr int RW  = D / 8;         // payload words per row
    const int gid = t / LPR, li = t % LPR;

    // stage this block's colidx range into LDS (mean 1024 entries; 2048 = +32 sigma)
    const int ebase = rowptr[r0];
    const int rend  = (r0 + 64 < NN) ? (r0 + 64) : NN;
    const int etot  = rowptr[rend] - ebase;
    const bool inlds = (etot <= 2048);
    if (inlds) {
        for (int i = t; i < etot; i += 256) cidxS[i] = colidx[ebase + i];
    }
    __syncthreads();

    // ---- phase 1: mean-aggregate into LDS (bf16, 16B-granule XOR-swizzled) ----
    for (int rr = gid; rr < 64; rr += GPB) {
        const int r = r0 + rr;
        float acc[16];
        #pragma unroll
        for (int k = 0; k < 16; ++k) acc[k] = 0.f;
        if (r < NN) {
            const int beg = rowptr[r], end = rowptr[r + 1];
            for (int e = beg; e < end; e += 8) {
                int sidx[8];
                if (inlds) {
                    #pragma unroll
                    for (int j = 0; j < 8; ++j)
                        sidx[j] = (e + j < end) ? cidxS[e + j - ebase] : -1;
                } else {
                    #pragma unroll
                    for (int j = 0; j < 8; ++j)
                        sidx[j] = (e + j < end) ? colidx[e + j] : -1;
                }
                uint2 u[8]; float sc[8];
                #pragma unroll
                for (int j = 0; j < 8; ++j) {
                    if (sidx[j] >= 0) {
                        u[j]  = *(const uint2*)(qin4 + (size_t)sidx[j] * RW + li * 2);
                        sc[j] = qs4[sidx[j]];
                    } else { u[j] = make_uint2(0u, 0u); sc[j] = 0.f; }
                }
                #pragma unroll
                for (int j = 0; j < 8; ++j) {
                    #pragma unroll
                    for (int wi = 0; wi < 2; ++wi) {
                        unsigned w = wi ? u[j].y : u[j].x;
                        #pragma unroll
                        for (int k = 0; k < 8; ++k) {
                            float f;
                            if (SIGNED) f = (float)((int)(w << (28 - 4 * k)) >> 28);
                            else        f = (float)((w >> (4 * k)) & 15u);
                            acc[wi * 8 + k] = fmaf(sc[j], f, acc[wi * 8 + k]);
                        }
                    }
                }
            }
            const float iv = invd[r];
            #pragma unroll
            for (int k = 0; k < 16; ++k) acc[k] *= iv;
        }
        #pragma unroll
        for (int gg = 0; gg < 2; ++gg) {
            unsigned q0 = (unsigned)f2bf(acc[gg*8+0]) | ((unsigned)f2bf(acc[gg*8+1]) << 16);
            unsigned q1 = (unsigned)f2bf(acc[gg*8+2]) | ((unsigned)f2bf(acc[gg*8+3]) << 16);
            unsigned q2 = (unsigned)f2bf(acc[gg*8+4]) | ((unsigned)f2bf(acc[gg*8+5]) << 16);
            unsigned q3 = (unsigned)f2bf(acc[gg*8+6]) | ((unsigned)f2bf(acc[gg*8+7]) << 16);
            int g  = li * 2 + gg;
            int gs = g ^ (rr & 7);
            *(uint4*)(aggSb + (size_t)rr * (D * 2) + (gs << 4)) = make_uint4(q0, q1, q2, q3);
        }
    }
    __syncthreads();

    // ---- phase 2: per-wave 16-row MFMA GEMM over HID in 16-col chunks ----
    const int w = t >> 6, l = t & 63, lm = l & 15, lk = l >> 4;
    const int rr = w * 16 + lm;
    const int rg = r0 + rr;

    bf16x8 ax[D / 32];
    if (SELF_F32) {
        const float* xf = (const float*)selfp;
        #pragma unroll
        for (int kk = 0; kk < D / 32; ++kk) {
            bf16x8 v;
            if (rg < NN) {
                const float4* p = (const float4*)(xf + (size_t)rg * D + kk * 32 + lk * 8);
                float4 f0 = p[0], f1 = p[1];
                v[0] = (short)f2bf(f0.x); v[1] = (short)f2bf(f0.y);
                v[2] = (short)f2bf(f0.z); v[3] = (short)f2bf(f0.w);
                v[4] = (short)f2bf(f1.x); v[5] = (short)f2bf(f1.y);
                v[6] = (short)f2bf(f1.z); v[7] = (short)f2bf(f1.w);
            } else v = (bf16x8)(short)0;
            ax[kk] = v;
        }
    } else {
        const char* hq = (const char*)selfp;
        const float sr = (rg < NN) ? selfs[rg] : 0.f;
        #pragma unroll
        for (int kk = 0; kk < D / 32; ++kk) {
            uint2 uq = (rg < NN)
                ? *(const uint2*)(hq + (size_t)rg * D + kk * 32 + lk * 8)
                : make_uint2(0u, 0u);
            bf16x8 v;
            v[0] = (short)f2bf(sr * sb(uq.x, 0));
            v[1] = (short)f2bf(sr * sb(uq.x, 1));
            v[2] = (short)f2bf(sr * sb(uq.x, 2));
            v[3] = (short)f2bf(sr * sb(uq.x, 3));
            v[4] = (short)f2bf(sr * sb(uq.y, 0));
            v[5] = (short)f2bf(sr * sb(uq.y, 1));
            v[6] = (short)f2bf(sr * sb(uq.y, 2));
            v[7] = (short)f2bf(sr * sb(uq.y, 3));
            ax[kk] = v;
        }
    }

    for (int cc = 0; cc < HID / 16; ++cc) {
        const int c = cc * 16 + lm;
        f32x4 acc = {0.f, 0.f, 0.f, 0.f};
        #pragma unroll
        for (int kk = 0; kk < D / 32; ++kk) {
            int g  = kk * 4 + lk;
            int gs = g ^ (rr & 7);
            bf16x8 a_agg = *(const bf16x8*)(aggSb + (size_t)rr * (D * 2) + (gs << 4));
            const size_t wf = ((size_t)(cc * (D / 32) + kk) * 64 + l) * 8;
            bf16x8 bl = *(const bf16x8*)(Wl + wf);
            bf16x8 br = *(const bf16x8*)(Wr + wf);
            acc = __builtin_amdgcn_mfma_f32_16x16x32_bf16(a_agg, bl, acc, 0, 0, 0);
            acc = __builtin_amdgcn_mfma_f32_16x16x32_bf16(ax[kk], br, acc, 0, 0, 0);
        }
        const float bv = bias[c];
        #pragma unroll
        for (int i = 0; i < 4; ++i) {
            const int orow = r0 + w * 16 + lk * 4 + i;
            if (orow < NN) {
                float v = fmaxf(acc[i] + bv, 0.f);
                hout[(size_t)orow * HID + c] = f2bf(v);
            }
        }
    }
}

// ---------------- premul: q = int8(h1@Wlo^T)+sq, r = h1@Wro^T+bo (frag-major weights) ----------------
__global__ __launch_bounds__(256, 4) void k_premul(
    const ushort* __restrict__ h1, const ushort* __restrict__ wlo,
    const ushort* __restrict__ wro, const float* __restrict__ bo,
    char* __restrict__ qq, float* __restrict__ sq, float* __restrict__ rbuf)
{
    const int t = threadIdx.x;
    const int r0 = blockIdx.x * 64;
    const int w = t >> 6, l = t & 63, lm = l & 15, lk = l >> 4;
    const int rr = w * 16 + lm;
    const int rg = r0 + rr;

    f32x4 aq[3], ar[3];
    #pragma unroll
    for (int cc = 0; cc < 3; ++cc) { aq[cc] = {0.f,0.f,0.f,0.f}; ar[cc] = {0.f,0.f,0.f,0.f}; }

    #pragma unroll
    for (int kk = 0; kk < 8; ++kk) {
        bf16x8 a = (rg < NN)
            ? *(const bf16x8*)(h1 + (size_t)rg * 256 + kk * 32 + lk * 8)
            : (bf16x8)(short)0;
        #pragma unroll
        for (int cc = 0; cc < 3; ++cc) {
            const size_t wf = ((size_t)(cc * 8 + kk) * 64 + l) * 8;
            bf16x8 bl = *(const bf16x8*)(wlo + wf);
            bf16x8 br = *(const bf16x8*)(wro + wf);
            aq[cc] = __builtin_amdgcn_mfma_f32_16x16x32_bf16(a, bl, aq[cc], 0, 0, 0);
            ar[cc] = __builtin_amdgcn_mfma_f32_16x16x32_bf16(a, br, ar[cc], 0, 0, 0);
        }
    }

    #pragma unroll
    for (int i = 0; i < 4; ++i) {
        const int orow = r0 + w * 16 + lk * 4 + i;
        if (orow >= NN) continue;
        float m = 0.f;
        #pragma unroll
        for (int cc = 0; cc < 3; ++cc) {
            const int c = cc * 16 + lm;
            if (c < OUTC) m = fmaxf(m, fabsf(aq[cc][i]));
        }
        m = fmaxf(m, __shfl_xor(m, 1));
        m = fmaxf(m, __shfl_xor(m, 2));
        m = fmaxf(m, __shfl_xor(m, 4));
        m = fmaxf(m, __shfl_xor(m, 8));
        const float inv = (m > 0.f) ? 127.f / m : 0.f;
        #pragma unroll
        for (int cc = 0; cc < 3; ++cc) {
            const int c = cc * 16 + lm;
            char qv = (c < OUTC) ? (char)(int)rintf(aq[cc][i] * inv) : (char)0;
            qq[(size_t)orow * 64 + c] = qv;
            rbuf[(size_t)orow * 64 + c] = (c < OUTC) ? (ar[cc][i] + bo[c]) : 0.f;
        }
        qq[(size_t)orow * 64 + 48 + lm] = (char)0;
        rbuf[(size_t)orow * 64 + 48 + lm] = 0.f;
        if (lm == 0) sq[orow] = m / 127.f;
    }
}

// ---------------- final: out = log_softmax(mean_agg(q) + r), 4 lanes per row ----------------
__global__ __launch_bounds__(256) void k_final(
    const char* __restrict__ qq, const float* __restrict__ sq,
    const float* __restrict__ rbuf, const float* __restrict__ invd,
    const int* __restrict__ rowptr, const int* __restrict__ colidx,
    float* __restrict__ out)
{
    const int t = threadIdx.x;
    const int g = t >> 2, li = t & 3;
    const int row = blockIdx.x * 64 + g;
    if (row >= NN) return;

    float acc[16];
    #pragma unroll
    for (int k = 0; k < 16; ++k) acc[k] = 0.f;

    const int beg = rowptr[row], end = rowptr[row + 1];
    for (int e = beg; e < end; e += 8) {
        int sidx[8];
        #pragma unroll
        for (int j = 0; j < 8; ++j) sidx[j] = (e + j < end) ? colidx[e + j] : -1;
        uint4 u[8]; float sc[8];
        #pragma unroll
        for (int j = 0; j < 8; ++j) {
            if (sidx[j] >= 0) {
                u[j]  = *(const uint4*)(qq + (size_t)sidx[j] * 64 + li * 16);
                sc[j] = sq[sidx[j]];
            } else { u[j] = make_uint4(0u, 0u, 0u, 0u); sc[j] = 0.f; }
        }
        #pragma unroll
        for (int j = 0; j < 8; ++j) {
            #pragma unroll
            for (int wi = 0; wi < 4; ++wi) {
                unsigned w = (&u[j].x)[wi];
                acc[wi*4+0] = fmaf(sc[j], sb(w, 0), acc[wi*4+0]);
                acc[wi*4+1] = fmaf(sc[j], sb(w, 1), acc[wi*4+1]);
                acc[wi*4+2] = fmaf(sc[j], sb(w, 2), acc[wi*4+2]);
                acc[wi*4+3] = fmaf(sc[j], sb(w, 3), acc[wi*4+3]);
            }
        }
    }

    const float iv = invd[row];
    const float4* rp = (const float4*)(rbuf + (size_t)row * 64 + li * 16);
    float v[16];
    #pragma unroll
    for (int ch = 0; ch < 4; ++ch) {
        float4 rv = rp[ch];
        v[ch*4+0] = acc[ch*4+0] * iv + rv.x;
        v[ch*4+1] = acc[ch*4+1] * iv + rv.y;
        v[ch*4+2] = acc[ch*4+2] * iv + rv.z;
        v[ch*4+3] = acc[ch*4+3] * iv + rv.w;
    }
    #pragma unroll
    for (int k = 0; k < 16; ++k)
        if (li * 16 + k >= OUTC) v[k] = -INFINITY;

    float m = v[0];
    #pragma unroll
    for (int k = 1; k < 16; ++k) m = fmaxf(m, v[k]);
    m = fmaxf(m, __shfl_xor(m, 1));
    m = fmaxf(m, __shfl_xor(m, 2));

    float s = 0.f;
    #pragma unroll
    for (int k = 0; k < 16; ++k)
        if (li * 16 + k < OUTC) s += __expf(v[k] - m);
    s += __shfl_xor(s, 1);
    s += __shfl_xor(s, 2);
    const float ls = __logf(s);

    #pragma unroll
    for (int ch = 0; ch < 4; ++ch) {
        const int c = li * 16 + ch * 4;
        if (c < OUTC) {
            float4 o;
            o.x = v[ch*4+0] - m - ls;
            o.y = v[ch*4+1] - m - ls;
            o.z = v[ch*4+2] - m - ls;
            o.w = v[ch*4+3] - m - ls;
            *(float4*)(out + (size_t)row * OUTC + c) = o;
        }
    }
}

extern "C" void kernel_launch(void* const* d_in, const int* in_sizes, int n_in,
                              void* d_out, int out_size, void* d_ws, size_t ws_size,
                              hipStream_t stream) {
    const float* x   = (const float*)d_in[0];
    const int*   ei  = (const int*)d_in[1];
    const int*   src = ei;
    const int*   dst = ei + NE;
    const float* Wl0 = (const float*)d_in[2];
    const float* Wr0 = (const float*)d_in[3];
    const float* b0  = (const float*)d_in[4];
    const float* Wl1 = (const float*)d_in[5];
    const float* Wr1 = (const float*)d_in[6];
    const float* b1  = (const float*)d_in[7];
    const float* Wlo = (const float*)d_in[8];
    const float* Wro = (const float*)d_in[9];
    const float* bo  = (const float*)d_in[10];
    float* out = (float*)d_out;

    char* ws = (char*)d_ws;
    const size_t MB = 1 << 20;
    float*    invd   = (float*)(ws + 0);
    int*      rowptr = (int*)(ws + MB / 2);
    int*      cnt    = (int*)(ws + MB);
    int*      fillp  = (int*)(ws + MB + MB / 2);
    int*      bsum   = (int*)(ws + 2 * MB);
    int*      boff   = (int*)(ws + 2 * MB + MB / 4);
    float*    sx4    = (float*)(ws + 2 * MB + MB / 2);
    float*    s8     = (float*)(ws + 3 * MB);
    float*    s4     = (float*)(ws + 3 * MB + MB / 2);
    float*    sq     = (float*)(ws + 4 * MB);
    ushort*   Wb     = (ushort*)(ws + 4 * MB + MB / 2);  // 442KB packed frag-major
    int*      colidx = (int*)(ws + 5 * MB + MB / 2);     // 6.4MB -> ends ~11.9
    unsigned* xq4    = (unsigned*)(ws + 12 * MB);        // [N][64B] = 6.4MB (12..18.4)
    char*     qq     = (char*)(ws + 12 * MB);            // aliases xq4 (dead after layer0)
    unsigned* h0q4   = (unsigned*)(ws + 19 * MB);        // [N][128B] = 12.8MB (19..31.8)
    ushort*   h0     = (ushort*)(ws + 32 * MB);          // [N,256] bf16 = 51.2MB (32..83.2)
    ushort*   h1     = (ushort*)(ws + 32 * MB);          // aliases h0 (self reads h0q8, not h0)
    char*     h0q8   = (char*)(ws + 84 * MB);            // [N,256] int8 = 25.6MB (84..109.6)
    float*    rbuf   = (float*)(ws + 84 * MB);           // aliases h0q8 (dead after layer1)

    ushort* wl0 = Wb;                 // 16*4*64*8  = 32768
    ushort* wr0 = Wb + 32768;
    ushort* wl1 = Wb + 65536;         // 16*8*64*8  = 65536
    ushort* wr1 = Wb + 131072;
    ushort* wlo = Wb + 196608;        // 3*8*64*8   = 12288 (48-row zero-padded)
    ushort* wro = Wb + 208896;

    // CSR build
    hipMemsetAsync(cnt, 0, NN * sizeof(int), stream);
    k_count<<<(NE + 255) / 256, 256, 0, stream>>>(dst, cnt);
    const int NB = (NN + 255) / 256;  // 391
    k_blocksum<<<NB, 256, 0, stream>>>(cnt, bsum);
    k_scanblock<<<1, 512, 0, stream>>>(bsum, boff, NB);
    k_rowptr<<<NB, 256, 0, stream>>>(cnt, boff, rowptr, fillp, invd);
    k_fill<<<(NE + 255) / 256, 256, 0, stream>>>(src, dst, fillp, colidx);

    // weights -> fragment-major bf16; x -> int4
    k_cvtfrag<<<16, 256, 0, stream>>>(Wl0, wl0, 256, 128, 4096);
    k_cvtfrag<<<16, 256, 0, stream>>>(Wr0, wr0, 256, 128, 4096);
    k_cvtfrag<<<32, 256, 0, stream>>>(Wl1, wl1, 256, 256, 8192);
    k_cvtfrag<<<32, 256, 0, stream>>>(Wr1, wr1, 256, 256, 8192);
    k_cvtfrag<<<6,  256, 0, stream>>>(Wlo, wlo, 40, 256, 1536);
    k_cvtfrag<<<6,  256, 0, stream>>>(Wro, wro, 40, 256, 1536);
    k_quant_x4<<<(NN + 15) / 16, 256, 0, stream>>>(x, xq4, sx4);

    const int GB = (NN + 63) / 64;  // 1563
    // layer 0: gather int4 x (1 line/edge), self fp32 x -> h0 bf16
    k_layer4<128, true, true><<<GB, 256, 0, stream>>>(
        xq4, sx4, x, nullptr, wl0, wr0, b0, invd, rowptr, colidx, h0);
    // quantize h0 -> int8 (self) + int4 (gather)
    k_quant_h84<<<(NN + 15) / 16, 256, 0, stream>>>(h0, h0q8, s8, h0q4, s4);
    // layer 1: gather int4 h0 (2 lines/edge), self int8 h0 -> h1 bf16 (aliases h0)
    k_layer4<256, false, false><<<GB, 256, 0, stream>>>(
        h0q4, s4, h0q8, s8, wl1, wr1, b1, invd, rowptr, colidx, h1);
    // layer 2 restructured: premul (+int8 quant of q), then 1-line-per-edge gather + softmax
    k_premul<<<GB, 256, 0, stream>>>(h1, wlo, wro, bo, qq, sq, rbuf);
    k_final<<<(NN + 63) / 64, 256, 0, stream>>>(qq, sq, rbuf, invd, rowptr, colidx, out);
}

// Round 10
// 513.364 us; speedup vs baseline: 3.1602x; 1.0184x over previous
//
#include <hip/hip_runtime.h>
#include <hip/hip_bf16.h>
#include <cstdint>
#include <cstddef>

#define NN   100000
#define NE   1600000
#define HID  256
#define OUTC 40

typedef __attribute__((ext_vector_type(8))) short bf16x8;
typedef __attribute__((ext_vector_type(4))) float f32x4;

static __device__ __forceinline__ ushort f2bf(float f) {
    __hip_bfloat16 h = __float2bfloat16(f);
    return *reinterpret_cast<ushort*>(&h);
}
static __device__ __forceinline__ float bflo(unsigned u) { return __uint_as_float(u << 16); }
static __device__ __forceinline__ float bfhi(unsigned u) { return __uint_as_float(u & 0xffff0000u); }
// unsigned byte k of word w -> float (selects to v_cvt_f32_ubyteN)
static __device__ __forceinline__ float ubf(unsigned w, int k) {
    return (float)((w >> (8 * k)) & 255u);
}

// ---------------- CSR build ----------------
__global__ void k_count(const int* __restrict__ dst, int* __restrict__ cnt) {
    int i = blockIdx.x * blockDim.x + threadIdx.x;
    if (i < NE) atomicAdd(&cnt[dst[i]], 1);
}

__global__ void k_blocksum(const int* __restrict__ cnt, int* __restrict__ bsum) {
    __shared__ int s[256];
    int t = threadIdx.x;
    int n = blockIdx.x * 256 + t;
    s[t] = (n < NN) ? cnt[n] : 0;
    __syncthreads();
    for (int off = 128; off; off >>= 1) {
        if (t < off) s[t] += s[t + off];
        __syncthreads();
    }
    if (t == 0) bsum[blockIdx.x] = s[0];
}

__global__ void k_scanblock(const int* __restrict__ bsum, int* __restrict__ boff, int nb) {
    __shared__ int s[512];
    int t = threadIdx.x;
    int v = (t < nb) ? bsum[t] : 0;
    s[t] = v;
    __syncthreads();
    for (int off = 1; off < 512; off <<= 1) {
        int u = (t >= off) ? s[t - off] : 0;
        __syncthreads();
        s[t] += u;
        __syncthreads();
    }
    if (t < nb) boff[t] = s[t] - v;
}

__global__ void k_rowptr(const int* __restrict__ cnt, const int* __restrict__ boff,
                         int* __restrict__ rowptr, int* __restrict__ fillp,
                         float* __restrict__ invd) {
    __shared__ int s[256];
    int t = threadIdx.x;
    int n = blockIdx.x * 256 + t;
    int c = (n < NN) ? cnt[n] : 0;
    s[t] = c;
    __syncthreads();
    for (int off = 1; off < 256; off <<= 1) {
        int u = (t >= off) ? s[t - off] : 0;
        __syncthreads();
        s[t] += u;
        __syncthreads();
    }
    if (n < NN) {
        int excl = boff[blockIdx.x] + s[t] - c;
        rowptr[n] = excl;
        fillp[n]  = excl;
        invd[n]   = 1.0f / (float)(c > 1 ? c : 1);
    }
    if (n == 0) rowptr[NN] = NE;
}

__global__ void k_fill(const int* __restrict__ src, const int* __restrict__ dst,
                       int* __restrict__ fillp, int* __restrict__ colidx) {
    int i = blockIdx.x * blockDim.x + threadIdx.x;
    if (i < NE) {
        int p = atomicAdd(&fillp[dst[i]], 1);
        colidx[p] = src[i];
    }
}

// ---------------- weights fp32 [OC][D] -> fragment-major bf16 ----------------
__global__ void k_cvtfrag(const float* __restrict__ W, ushort* __restrict__ dst,
                          int ocreal, int d, int nf) {
    int f = blockIdx.x * 256 + threadIdx.x;
    if (f >= nf) return;
    int lm = f & 15, lk = (f >> 4) & 3;
    int rest = f >> 6;
    int dk = d / 32;
    int kk = rest % dk, cc = rest / dk;
    int row = cc * 16 + lm, col = kk * 32 + lk * 8;
    unsigned q0 = 0, q1 = 0, q2 = 0, q3 = 0;
    if (row < ocreal) {
        const float4* p = (const float4*)(W + (size_t)row * d + col);
        float4 a = p[0], b = p[1];
        q0 = (unsigned)f2bf(a.x) | ((unsigned)f2bf(a.y) << 16);
        q1 = (unsigned)f2bf(a.z) | ((unsigned)f2bf(a.w) << 16);
        q2 = (unsigned)f2bf(b.x) | ((unsigned)f2bf(b.y) << 16);
        q3 = (unsigned)f2bf(b.z) | ((unsigned)f2bf(b.w) << 16);
    }
    *(uint4*)(dst + (size_t)f * 8) = make_uint4(q0, q1, q2, q3);
}

// ---------------- x fp32 [N,128] -> biased u8 (code = rint(v*127/m)+128), scale sx = m/127 ----------------
__global__ __launch_bounds__(256) void k_quant_x8(const float* __restrict__ x,
                                                  unsigned char* __restrict__ xq,
                                                  float* __restrict__ sx) {
    int t = threadIdx.x;
    int qw = t >> 4, ql = t & 15;
    int row = blockIdx.x * 16 + qw;
    if (row >= NN) return;
    const float4* p = (const float4*)(x + (size_t)row * 128 + ql * 8);
    float4 a = p[0], b = p[1];
    float v[8] = {a.x, a.y, a.z, a.w, b.x, b.y, b.z, b.w};
    float m = 0.f;
    #pragma unroll
    for (int k = 0; k < 8; ++k) m = fmaxf(m, fabsf(v[k]));
    m = fmaxf(m, __shfl_xor(m, 1));
    m = fmaxf(m, __shfl_xor(m, 2));
    m = fmaxf(m, __shfl_xor(m, 4));
    m = fmaxf(m, __shfl_xor(m, 8));
    float inv = (m > 0.f) ? 127.f / m : 0.f;
    unsigned w0 = 0, w1 = 0;
    #pragma unroll
    for (int k = 0; k < 4; ++k)
        w0 |= ((unsigned)((int)rintf(v[k] * inv) + 128) & 255u) << (8 * k);
    #pragma unroll
    for (int k = 0; k < 4; ++k)
        w1 |= ((unsigned)((int)rintf(v[4 + k] * inv) + 128) & 255u) << (8 * k);
    *(uint2*)(xq + (size_t)row * 128 + ql * 8) = make_uint2(w0, w1);
    if (ql == 0) sx[row] = (m > 0.f) ? m / 127.f : 0.f;
}

// ---------------- h0 bf16 [N,256] (>=0) -> unsigned u8 (code = rint(v*255/m)), scale = m/255 ----------------
__global__ __launch_bounds__(256) void k_quant_h8(const ushort* __restrict__ h,
                                                  unsigned char* __restrict__ hq,
                                                  float* __restrict__ s8) {
    int t = threadIdx.x;
    int qw = t >> 4, ql = t & 15;
    int row = blockIdx.x * 16 + qw;
    if (row >= NN) return;
    const uint4* p = (const uint4*)(h + (size_t)row * 256 + ql * 16);
    uint4 a = p[0], b = p[1];
    float v[16];
    v[0]  = bflo(a.x); v[1]  = bfhi(a.x); v[2]  = bflo(a.y); v[3]  = bfhi(a.y);
    v[4]  = bflo(a.z); v[5]  = bfhi(a.z); v[6]  = bflo(a.w); v[7]  = bfhi(a.w);
    v[8]  = bflo(b.x); v[9]  = bfhi(b.x); v[10] = bflo(b.y); v[11] = bfhi(b.y);
    v[12] = bflo(b.z); v[13] = bfhi(b.z); v[14] = bflo(b.w); v[15] = bfhi(b.w);
    float m = 0.f;
    #pragma unroll
    for (int k = 0; k < 16; ++k) m = fmaxf(m, v[k]);   // h >= 0
    m = fmaxf(m, __shfl_xor(m, 1));
    m = fmaxf(m, __shfl_xor(m, 2));
    m = fmaxf(m, __shfl_xor(m, 4));
    m = fmaxf(m, __shfl_xor(m, 8));
    float inv = (m > 0.f) ? 255.f / m : 0.f;
    unsigned wo[4];
    #pragma unroll
    for (int wi = 0; wi < 4; ++wi) {
        unsigned w = 0;
        #pragma unroll
        for (int k = 0; k < 4; ++k)
            w |= ((unsigned)(int)rintf(v[wi * 4 + k] * inv) & 255u) << (8 * k);
        wo[wi] = w;
    }
    *(uint4*)(hq + (size_t)row * 256 + ql * 16) = make_uint4(wo[0], wo[1], wo[2], wo[3]);
    if (ql == 0) s8[row] = (m > 0.f) ? m / 255.f : 0.f;
}

// ---------------- fused layer: u8 CSR mean-aggregate (LDS) + dual bf16 MFMA GEMM ----------------
// Phase 1: D/16 lanes/row, 16 u8 feats (uint4) per lane, 8-edge predicated batches.
// colidx+scale loaded lane-parallel (1 each per lane per batch) and __shfl-broadcast.
// BIASED: codes are v*inv+128; correction -128*sum_sc applied at dequant (exact).
// Phase 2: frag-major weights; self from fp32 x (layer0) or the same u8 buffer (layer1).
template<int D, bool SELF_F32, bool BIASED>
__global__ __launch_bounds__(256, 4) void k_layer8u(
    const unsigned char* __restrict__ qin, const float* __restrict__ qs,
    const float* __restrict__ xf,          // layer0 self (fp32) or nullptr
    const ushort* __restrict__ Wl, const ushort* __restrict__ Wr,   // frag-major
    const float* __restrict__ bias, const float* __restrict__ invd,
    const int* __restrict__ rowptr, const int* __restrict__ colidx,
    ushort* __restrict__ hout)
{
    __shared__ ushort aggS[64 * D];
    __shared__ int cidxS[2048];
    char* aggSb = (char*)aggS;
    const int t  = threadIdx.x;
    const int r0 = blockIdx.x * 64;
    constexpr int LPR = D / 16;        // lanes per row (8 or 16)
    constexpr int GPB = 256 / LPR;     // row-groups per block
    constexpr int RSH = (D == 128) ? 7 : 8;   // row byte shift
    const int gid = t / LPR, li = t % LPR;
    const int l = t & 63;
    const int base = l & ~(LPR - 1);

    // stage block's colidx range into LDS
    const int ebase = rowptr[r0];
    const int rend  = (r0 + 64 < NN) ? (r0 + 64) : NN;
    const int etot  = rowptr[rend] - ebase;
    const bool inlds = (etot <= 2048);
    if (inlds) {
        for (int i = t; i < etot; i += 256) cidxS[i] = colidx[ebase + i];
    }
    __syncthreads();

    // ---- phase 1 ----
    for (int rr = gid; rr < 64; rr += GPB) {
        const int r = r0 + rr;
        float acc[16];
        #pragma unroll
        for (int k = 0; k < 16; ++k) acc[k] = 0.f;
        float sum_sc = 0.f;
        if (r < NN) {
            const int beg = rowptr[r], end = rowptr[r + 1];
            for (int e = beg; e < end; e += 8) {
                // lane-parallel colidx + scale (one each), broadcast via shfl
                const int myi = e + (li & 7);
                int se = -1;
                if (myi < end) se = inlds ? cidxS[myi - ebase] : colidx[myi];
                float mysc = (se >= 0) ? qs[se] : 0.f;
                int   sj[8];
                float sc[8];
                uint4 u[8];
                #pragma unroll
                for (int j = 0; j < 8; ++j) sj[j] = __shfl(se, base + j);
                #pragma unroll
                for (int j = 0; j < 8; ++j) sc[j] = __shfl(mysc, base + j);
                #pragma unroll
                for (int j = 0; j < 8; ++j) {
                    u[j] = (sj[j] >= 0)
                        ? *(const uint4*)(qin + (((unsigned)sj[j]) << RSH) + (li << 4))
                        : make_uint4(0u, 0u, 0u, 0u);
                }
                #pragma unroll
                for (int j = 0; j < 8; ++j) {
                    #pragma unroll
                    for (int wi = 0; wi < 4; ++wi) {
                        unsigned w = (&u[j].x)[wi];
                        acc[wi*4+0] = fmaf(sc[j], ubf(w, 0), acc[wi*4+0]);
                        acc[wi*4+1] = fmaf(sc[j], ubf(w, 1), acc[wi*4+1]);
                        acc[wi*4+2] = fmaf(sc[j], ubf(w, 2), acc[wi*4+2]);
                        acc[wi*4+3] = fmaf(sc[j], ubf(w, 3), acc[wi*4+3]);
                    }
                    if (BIASED) sum_sc += sc[j];
                }
            }
            const float iv = invd[r];
            #pragma unroll
            for (int k = 0; k < 16; ++k) {
                if (BIASED) acc[k] = (acc[k] - 128.f * sum_sc) * iv;
                else        acc[k] = acc[k] * iv;
            }
        }
        #pragma unroll
        for (int gg = 0; gg < 2; ++gg) {
            unsigned q0 = (unsigned)f2bf(acc[gg*8+0]) | ((unsigned)f2bf(acc[gg*8+1]) << 16);
            unsigned q1 = (unsigned)f2bf(acc[gg*8+2]) | ((unsigned)f2bf(acc[gg*8+3]) << 16);
            unsigned q2 = (unsigned)f2bf(acc[gg*8+4]) | ((unsigned)f2bf(acc[gg*8+5]) << 16);
            unsigned q3 = (unsigned)f2bf(acc[gg*8+6]) | ((unsigned)f2bf(acc[gg*8+7]) << 16);
            int g  = li * 2 + gg;
            int gs = g ^ (rr & 7);
            *(uint4*)(aggSb + (size_t)rr * (D * 2) + (gs << 4)) = make_uint4(q0, q1, q2, q3);
        }
    }
    __syncthreads();

    // ---- phase 2: per-wave 16-row MFMA GEMM over HID in 16-col chunks ----
    const int w = t >> 6, lm = l & 15, lk = l >> 4;
    const int rr = w * 16 + lm;
    const int rg = r0 + rr;

    bf16x8 ax[D / 32];
    if (SELF_F32) {
        #pragma unroll
        for (int kk = 0; kk < D / 32; ++kk) {
            bf16x8 v;
            if (rg < NN) {
                const float4* p = (const float4*)(xf + (size_t)rg * D + kk * 32 + lk * 8);
                float4 f0 = p[0], f1 = p[1];
                v[0] = (short)f2bf(f0.x); v[1] = (short)f2bf(f0.y);
                v[2] = (short)f2bf(f0.z); v[3] = (short)f2bf(f0.w);
                v[4] = (short)f2bf(f1.x); v[5] = (short)f2bf(f1.y);
                v[6] = (short)f2bf(f1.z); v[7] = (short)f2bf(f1.w);
            } else v = (bf16x8)(short)0;
            ax[kk] = v;
        }
    } else {
        const float sr = (rg < NN) ? qs[rg] : 0.f;
        #pragma unroll
        for (int kk = 0; kk < D / 32; ++kk) {
            uint2 uq = (rg < NN)
                ? *(const uint2*)(qin + (((unsigned)rg) << RSH) + kk * 32 + lk * 8)
                : make_uint2(0u, 0u);
            bf16x8 v;
            v[0] = (short)f2bf(sr * ubf(uq.x, 0));
            v[1] = (short)f2bf(sr * ubf(uq.x, 1));
            v[2] = (short)f2bf(sr * ubf(uq.x, 2));
            v[3] = (short)f2bf(sr * ubf(uq.x, 3));
            v[4] = (short)f2bf(sr * ubf(uq.y, 0));
            v[5] = (short)f2bf(sr * ubf(uq.y, 1));
            v[6] = (short)f2bf(sr * ubf(uq.y, 2));
            v[7] = (short)f2bf(sr * ubf(uq.y, 3));
            ax[kk] = v;
        }
    }

    for (int cc = 0; cc < HID / 16; ++cc) {
        const int c = cc * 16 + lm;
        f32x4 acc = {0.f, 0.f, 0.f, 0.f};
        #pragma unroll
        for (int kk = 0; kk < D / 32; ++kk) {
            int g  = kk * 4 + lk;
            int gs = g ^ (rr & 7);
            bf16x8 a_agg = *(const bf16x8*)(aggSb + (size_t)rr * (D * 2) + (gs << 4));
            const size_t wf = ((size_t)(cc * (D / 32) + kk) * 64 + l) * 8;
            bf16x8 bl = *(const bf16x8*)(Wl + wf);
            bf16x8 br = *(const bf16x8*)(Wr + wf);
            acc = __builtin_amdgcn_mfma_f32_16x16x32_bf16(a_agg, bl, acc, 0, 0, 0);
            acc = __builtin_amdgcn_mfma_f32_16x16x32_bf16(ax[kk], br, acc, 0, 0, 0);
        }
        const float bv = bias[c];
        #pragma unroll
        for (int i = 0; i < 4; ++i) {
            const int orow = r0 + w * 16 + lk * 4 + i;
            if (orow < NN) {
                float v = fmaxf(acc[i] + bv, 0.f);
                hout[(size_t)orow * HID + c] = f2bf(v);
            }
        }
    }
}

// ---------------- premul: qq = biased-u8(h1@Wlo^T)+sq, rbuf = h1@Wro^T+bo ----------------
__global__ __launch_bounds__(256, 4) void k_premul(
    const ushort* __restrict__ h1, const ushort* __restrict__ wlo,
    const ushort* __restrict__ wro, const float* __restrict__ bo,
    unsigned char* __restrict__ qq, float* __restrict__ sq, float* __restrict__ rbuf)
{
    const int t = threadIdx.x;
    const int r0 = blockIdx.x * 64;
    const int w = t >> 6, l = t & 63, lm = l & 15, lk = l >> 4;
    const int rr = w * 16 + lm;
    const int rg = r0 + rr;

    f32x4 aq[3], ar[3];
    #pragma unroll
    for (int cc = 0; cc < 3; ++cc) { aq[cc] = {0.f,0.f,0.f,0.f}; ar[cc] = {0.f,0.f,0.f,0.f}; }

    #pragma unroll
    for (int kk = 0; kk < 8; ++kk) {
        bf16x8 a = (rg < NN)
            ? *(const bf16x8*)(h1 + (size_t)rg * 256 + kk * 32 + lk * 8)
            : (bf16x8)(short)0;
        #pragma unroll
        for (int cc = 0; cc < 3; ++cc) {
            const size_t wf = ((size_t)(cc * 8 + kk) * 64 + l) * 8;
            bf16x8 bl = *(const bf16x8*)(wlo + wf);
            bf16x8 br = *(const bf16x8*)(wro + wf);
            aq[cc] = __builtin_amdgcn_mfma_f32_16x16x32_bf16(a, bl, aq[cc], 0, 0, 0);
            ar[cc] = __builtin_amdgcn_mfma_f32_16x16x32_bf16(a, br, ar[cc], 0, 0, 0);
        }
    }

    #pragma unroll
    for (int i = 0; i < 4; ++i) {
        const int orow = r0 + w * 16 + lk * 4 + i;
        if (orow >= NN) continue;
        float m = 0.f;
        #pragma unroll
        for (int cc = 0; cc < 3; ++cc) {
            const int c = cc * 16 + lm;
            if (c < OUTC) m = fmaxf(m, fabsf(aq[cc][i]));
        }
        m = fmaxf(m, __shfl_xor(m, 1));
        m = fmaxf(m, __shfl_xor(m, 2));
        m = fmaxf(m, __shfl_xor(m, 4));
        m = fmaxf(m, __shfl_xor(m, 8));
        const float inv = (m > 0.f) ? 127.f / m : 0.f;
        #pragma unroll
        for (int cc = 0; cc < 3; ++cc) {
            const int c = cc * 16 + lm;
            int code = (c < OUTC) ? (int)rintf(aq[cc][i] * inv) : 0;
            qq[(size_t)orow * 64 + c] = (unsigned char)(code + 128);
            rbuf[(size_t)orow * 64 + c] = (c < OUTC) ? (ar[cc][i] + bo[c]) : 0.f;
        }
        qq[(size_t)orow * 64 + 48 + lm] = (unsigned char)128;
        rbuf[(size_t)orow * 64 + 48 + lm] = 0.f;
        if (lm == 0) sq[orow] = m / 127.f;
    }
}

// ---------------- final: out = log_softmax(mean_agg(q) + r), 4 lanes per row ----------------
__global__ __launch_bounds__(256) void k_final(
    const unsigned char* __restrict__ qq, const float* __restrict__ sq,
    const float* __restrict__ rbuf, const float* __restrict__ invd,
    const int* __restrict__ rowptr, const int* __restrict__ colidx,
    float* __restrict__ out)
{
    __shared__ int cidxS[2048];
    const int t = threadIdx.x;
    const int g = t >> 2, li = t & 3;
    const int r0 = blockIdx.x * 64;
    const int row = r0 + g;
    const int l = t & 63;
    const int base = l & ~3;

    const int ebase = rowptr[r0];
    const int rend  = (r0 + 64 < NN) ? (r0 + 64) : NN;
    const int etot  = rowptr[rend] - ebase;
    const bool inlds = (etot <= 2048);
    if (inlds) {
        for (int i = t; i < etot; i += 256) cidxS[i] = colidx[ebase + i];
    }
    __syncthreads();
    if (row >= NN) return;

    float acc[16];
    #pragma unroll
    for (int k = 0; k < 16; ++k) acc[k] = 0.f;
    float sum_sc = 0.f;

    const int beg = rowptr[row], end = rowptr[row + 1];
    for (int e = beg; e < end; e += 8) {
        const int m0 = e + li, m1 = e + 4 + li;
        int se0 = -1, se1 = -1;
        if (m0 < end) se0 = inlds ? cidxS[m0 - ebase] : colidx[m0];
        if (m1 < end) se1 = inlds ? cidxS[m1 - ebase] : colidx[m1];
        float ms0 = (se0 >= 0) ? sq[se0] : 0.f;
        float ms1 = (se1 >= 0) ? sq[se1] : 0.f;
        int   sj[8];
        float sc[8];
        uint4 u[8];
        #pragma unroll
        for (int j = 0; j < 4; ++j) { sj[j] = __shfl(se0, base + j); sc[j] = __shfl(ms0, base + j); }
        #pragma unroll
        for (int j = 4; j < 8; ++j) { sj[j] = __shfl(se1, base + j - 4); sc[j] = __shfl(ms1, base + j - 4); }
        #pragma unroll
        for (int j = 0; j < 8; ++j) {
            u[j] = (sj[j] >= 0)
                ? *(const uint4*)(qq + (((unsigned)sj[j]) << 6) + (li << 4))
                : make_uint4(0u, 0u, 0u, 0u);
        }
        #pragma unroll
        for (int j = 0; j < 8; ++j) {
            #pragma unroll
            for (int wi = 0; wi < 4; ++wi) {
                unsigned w = (&u[j].x)[wi];
                acc[wi*4+0] = fmaf(sc[j], ubf(w, 0), acc[wi*4+0]);
                acc[wi*4+1] = fmaf(sc[j], ubf(w, 1), acc[wi*4+1]);
                acc[wi*4+2] = fmaf(sc[j], ubf(w, 2), acc[wi*4+2]);
                acc[wi*4+3] = fmaf(sc[j], ubf(w, 3), acc[wi*4+3]);
            }
            sum_sc += sc[j];
        }
    }

    const float iv = invd[row];
    const float4* rp = (const float4*)(rbuf + (size_t)row * 64 + li * 16);
    float v[16];
    #pragma unroll
    for (int ch = 0; ch < 4; ++ch) {
        float4 rv = rp[ch];
        v[ch*4+0] = (acc[ch*4+0] - 128.f * sum_sc) * iv + rv.x;
        v[ch*4+1] = (acc[ch*4+1] - 128.f * sum_sc) * iv + rv.y;
        v[ch*4+2] = (acc[ch*4+2] - 128.f * sum_sc) * iv + rv.z;
        v[ch*4+3] = (acc[ch*4+3] - 128.f * sum_sc) * iv + rv.w;
    }
    #pragma unroll
    for (int k = 0; k < 16; ++k)
        if (li * 16 + k >= OUTC) v[k] = -INFINITY;

    float m = v[0];
    #pragma unroll
    for (int k = 1; k < 16; ++k) m = fmaxf(m, v[k]);
    m = fmaxf(m, __shfl_xor(m, 1));
    m = fmaxf(m, __shfl_xor(m, 2));

    float s = 0.f;
    #pragma unroll
    for (int k = 0; k < 16; ++k)
        if (li * 16 + k < OUTC) s += __expf(v[k] - m);
    s += __shfl_xor(s, 1);
    s += __shfl_xor(s, 2);
    const float ls = __logf(s);

    #pragma unroll
    for (int ch = 0; ch < 4; ++ch) {
        const int c = li * 16 + ch * 4;
        if (c < OUTC) {
            float4 o;
            o.x = v[ch*4+0] - m - ls;
            o.y = v[ch*4+1] - m - ls;
            o.z = v[ch*4+2] - m - ls;
            o.w = v[ch*4+3] - m - ls;
            *(float4*)(out + (size_t)row * OUTC + c) = o;
        }
    }
}

extern "C" void kernel_launch(void* const* d_in, const int* in_sizes, int n_in,
                              void* d_out, int out_size, void* d_ws, size_t ws_size,
                              hipStream_t stream) {
    const float* x   = (const float*)d_in[0];
    const int*   ei  = (const int*)d_in[1];
    const int*   src = ei;
    const int*   dst = ei + NE;
    const float* Wl0 = (const float*)d_in[2];
    const float* Wr0 = (const float*)d_in[3];
    const float* b0  = (const float*)d_in[4];
    const float* Wl1 = (const float*)d_in[5];
    const float* Wr1 = (const float*)d_in[6];
    const float* b1  = (const float*)d_in[7];
    const float* Wlo = (const float*)d_in[8];
    const float* Wro = (const float*)d_in[9];
    const float* bo  = (const float*)d_in[10];
    float* out = (float*)d_out;

    char* ws = (char*)d_ws;
    const size_t MB = 1 << 20;
    float*         invd   = (float*)(ws + 0);
    int*           rowptr = (int*)(ws + MB / 2);
    int*           cnt    = (int*)(ws + MB);
    int*           fillp  = (int*)(ws + MB + MB / 2);
    int*           bsum   = (int*)(ws + 2 * MB);
    int*           boff   = (int*)(ws + 2 * MB + MB / 4);
    float*         sx     = (float*)(ws + 2 * MB + MB / 2);
    float*         s8     = (float*)(ws + 3 * MB);
    float*         sq     = (float*)(ws + 4 * MB);
    ushort*        Wb     = (ushort*)(ws + 4 * MB + MB / 2);  // 442KB frag-major
    int*           colidx = (int*)(ws + 5 * MB + MB / 2);     // 6.4MB -> ends ~11.9
    unsigned char* xq8    = (unsigned char*)(ws + 12 * MB);   // [N,128] u8 = 12.8MB (12..24.8)
    unsigned char* qq     = (unsigned char*)(ws + 12 * MB);   // aliases xq8 (dead after layer0)
    ushort*        h0     = (ushort*)(ws + 32 * MB);          // [N,256] bf16 = 51.2MB (32..83.2)
    ushort*        h1     = (ushort*)(ws + 32 * MB);          // aliases h0 (self reads h0q8u)
    unsigned char* h0q8u  = (unsigned char*)(ws + 84 * MB);   // [N,256] u8 = 25.6MB (84..109.6)
    float*         rbuf   = (float*)(ws + 84 * MB);           // aliases h0q8u (dead after layer1)

    ushort* wl0 = Wb;                 // 16*4*64*8  = 32768
    ushort* wr0 = Wb + 32768;
    ushort* wl1 = Wb + 65536;         // 16*8*64*8  = 65536
    ushort* wr1 = Wb + 131072;
    ushort* wlo = Wb + 196608;        // 3*8*64*8   = 12288 (48-row zero-padded)
    ushort* wro = Wb + 208896;

    // CSR build
    hipMemsetAsync(cnt, 0, NN * sizeof(int), stream);
    k_count<<<(NE + 255) / 256, 256, 0, stream>>>(dst, cnt);
    const int NB = (NN + 255) / 256;  // 391
    k_blocksum<<<NB, 256, 0, stream>>>(cnt, bsum);
    k_scanblock<<<1, 512, 0, stream>>>(bsum, boff, NB);
    k_rowptr<<<NB, 256, 0, stream>>>(cnt, boff, rowptr, fillp, invd);
    k_fill<<<(NE + 255) / 256, 256, 0, stream>>>(src, dst, fillp, colidx);

    // weights -> fragment-major bf16; x -> biased u8
    k_cvtfrag<<<16, 256, 0, stream>>>(Wl0, wl0, 256, 128, 4096);
    k_cvtfrag<<<16, 256, 0, stream>>>(Wr0, wr0, 256, 128, 4096);
    k_cvtfrag<<<32, 256, 0, stream>>>(Wl1, wl1, 256, 256, 8192);
    k_cvtfrag<<<32, 256, 0, stream>>>(Wr1, wr1, 256, 256, 8192);
    k_cvtfrag<<<6,  256, 0, stream>>>(Wlo, wlo, 40, 256, 1536);
    k_cvtfrag<<<6,  256, 0, stream>>>(Wro, wro, 40, 256, 1536);
    k_quant_x8<<<(NN + 15) / 16, 256, 0, stream>>>(x, xq8, sx);

    const int GB = (NN + 63) / 64;  // 1563
    // layer 0: gather biased-u8 x, self fp32 x -> h0 bf16
    k_layer8u<128, true, true><<<GB, 256, 0, stream>>>(
        xq8, sx, x, wl0, wr0, b0, invd, rowptr, colidx, h0);
    // quantize h0 -> unsigned u8 (serves gather AND self)
    k_quant_h8<<<(NN + 15) / 16, 256, 0, stream>>>(h0, h0q8u, s8);
    // layer 1: gather u8 h0, self u8 h0 -> h1 bf16 (aliases h0)
    k_layer8u<256, false, false><<<GB, 256, 0, stream>>>(
        h0q8u, s8, nullptr, wl1, wr1, b1, invd, rowptr, colidx, h1);
    // layer 2: premul (+biased-u8 quant of q), then 1-line-per-edge gather + softmax
    k_premul<<<GB, 256, 0, stream>>>(h1, wlo, wro, bo, qq, sq, rbuf);
    k_final<<<(NN + 63) / 64, 256, 0, stream>>>(qq, sq, rbuf, invd, rowptr, colidx, out);
}